// Round 1
// baseline (1885.298 us; speedup 1.0000x reference)
//
#include <hip/hip_runtime.h>
#include <math.h>

#define N_NODES 150000
#define D 64
#define NEDGE 4800000
#define NUM_LAYERS 3

#define SCAN_BLOCK 256
#define SCAN_CHUNK 2048  // 256 threads * 8 elems
#define NSCAN_BLOCKS ((N_NODES + SCAN_CHUNK - 1) / SCAN_CHUNK)  // 74

// ---- degree count (int atomics, deterministic) ----
__global__ void deg_kernel(const int* __restrict__ col, int* __restrict__ deg) {
    int i = blockIdx.x * blockDim.x + threadIdx.x;
    int stride = gridDim.x * blockDim.x;
    for (int e = i; e < NEDGE; e += stride)
        atomicAdd(&deg[col[e]], 1);
}

// ---- deg_inv_sqrt ----
__global__ void dis_kernel(const int* __restrict__ deg, float* __restrict__ dis) {
    int i = blockIdx.x * blockDim.x + threadIdx.x;
    if (i < N_NODES) {
        int d = deg[i];
        dis[i] = (d > 0) ? (1.0f / sqrtf((float)d)) : 0.0f;
    }
}

// ---- exclusive scan of deg -> off (3-kernel, N=150k) ----
__global__ void scan1(const int* __restrict__ deg, int* __restrict__ off,
                      int* __restrict__ blk_sums) {
    __shared__ int tsum[SCAN_BLOCK];
    int b = blockIdx.x, t = threadIdx.x;
    int base = b * SCAN_CHUNK + t * 8;
    int v[8];
    int s = 0;
#pragma unroll
    for (int k = 0; k < 8; k++) {
        int idx = base + k;
        v[k] = (idx < N_NODES) ? deg[idx] : 0;
        s += v[k];
    }
    tsum[t] = s;
    __syncthreads();
    // Hillis-Steele inclusive scan over 256 thread sums
    for (int ofs = 1; ofs < SCAN_BLOCK; ofs <<= 1) {
        int xv = (t >= ofs) ? tsum[t - ofs] : 0;
        __syncthreads();
        tsum[t] += xv;
        __syncthreads();
    }
    int excl = (t > 0) ? tsum[t - 1] : 0;
    if (t == SCAN_BLOCK - 1) blk_sums[b] = tsum[t];
    int run = excl;
#pragma unroll
    for (int k = 0; k < 8; k++) {
        int idx = base + k;
        if (idx < N_NODES) off[idx] = run;
        run += v[k];
    }
}

__global__ void scan2(const int* __restrict__ blk_sums, int* __restrict__ blk_off) {
    if (threadIdx.x == 0) {
        int run = 0;
        for (int b = 0; b < NSCAN_BLOCKS; b++) {
            blk_off[b] = run;
            run += blk_sums[b];
        }
    }
}

__global__ void scan3(int* __restrict__ off, const int* __restrict__ blk_off,
                      int* __restrict__ cursor) {
    int i = blockIdx.x * blockDim.x + threadIdx.x;
    if (i < N_NODES) {
        int v = off[i] + blk_off[i / SCAN_CHUNK];
        off[i] = v;
        cursor[i] = v;
    }
    if (i == 0) off[N_NODES] = NEDGE;
}

// ---- scatter rows into CSR order by destination ----
__global__ void scatter_kernel(const int* __restrict__ row, const int* __restrict__ col,
                               int* __restrict__ cursor, int* __restrict__ rows_sorted) {
    int i = blockIdx.x * blockDim.x + threadIdx.x;
    int stride = gridDim.x * blockDim.x;
    for (int e = i; e < NEDGE; e += stride) {
        int c = col[e];
        int pos = atomicAdd(&cursor[c], 1);
        rows_sorted[pos] = row[e];
    }
}

// ---- one propagation layer: wave per dest node, lane per feature dim ----
template <bool WRITE_H, bool ACCUM_OUT>
__global__ void layer_kernel(const float* __restrict__ h, const int* __restrict__ off,
                             const int* __restrict__ rows_sorted,
                             const float* __restrict__ dis, float* __restrict__ hout,
                             float* __restrict__ out, float alpha) {
    int wid = (blockIdx.x * blockDim.x + threadIdx.x) >> 6;
    int lane = threadIdx.x & 63;
    if (wid >= N_NODES) return;
    int start = off[wid];
    int end = off[wid + 1];
    float acc = 0.0f;
    for (int e = start; e < end; e++) {
        int r = rows_sorted[e];
        float w = dis[r];
        acc += w * h[(size_t)r * D + lane];
    }
    float val = dis[wid] * acc;
    size_t o = (size_t)wid * D + lane;
    if (WRITE_H) hout[o] = val;
    if (ACCUM_OUT)
        out[o] = out[o] + alpha * val;
    else
        out[o] = alpha * val;
}

extern "C" void kernel_launch(void* const* d_in, const int* in_sizes, int n_in,
                              void* d_out, int out_size, void* d_ws, size_t ws_size,
                              hipStream_t stream) {
    const float* x = (const float*)d_in[0];
    const int* edges = (const int*)d_in[1];
    const int* row = edges;           // edge_index[0]
    const int* col = edges + NEDGE;   // edge_index[1]
    float* out = (float*)d_out;

    char* ws = (char*)d_ws;
    size_t p = 0;
    auto alloc = [&](size_t bytes) {
        void* r = ws + p;
        p += (bytes + 255) & ~(size_t)255;
        return r;
    };
    int* deg = (int*)alloc((size_t)N_NODES * 4);
    float* dis = (float*)alloc((size_t)N_NODES * 4);
    int* off = (int*)alloc((size_t)(N_NODES + 1) * 4);
    int* cursor = (int*)alloc((size_t)N_NODES * 4);
    int* blk_sums = (int*)alloc((size_t)NSCAN_BLOCKS * 4);
    int* blk_off = (int*)alloc((size_t)NSCAN_BLOCKS * 4);
    int* rows_sorted = (int*)alloc((size_t)NEDGE * 4);
    float* hA = (float*)alloc((size_t)N_NODES * D * 4);
    float* hB = (float*)alloc((size_t)N_NODES * D * 4);

    hipMemsetAsync(deg, 0, (size_t)N_NODES * 4, stream);
    deg_kernel<<<2048, 256, 0, stream>>>(col, deg);
    int nblk_n = (N_NODES + 255) / 256;
    dis_kernel<<<nblk_n, 256, 0, stream>>>(deg, dis);
    scan1<<<NSCAN_BLOCKS, SCAN_BLOCK, 0, stream>>>(deg, off, blk_sums);
    scan2<<<1, 64, 0, stream>>>(blk_sums, blk_off);
    scan3<<<nblk_n, 256, 0, stream>>>(off, blk_off, cursor);
    scatter_kernel<<<2048, 256, 0, stream>>>(row, col, cursor, rows_sorted);

    const float alpha = 1.0f / (1.0f + NUM_LAYERS);
    int grid = (N_NODES * D + 255) / 256;  // one wave64 per node, 4 waves/block
    layer_kernel<true, false><<<grid, 256, 0, stream>>>(x, off, rows_sorted, dis, hA, out, alpha);
    layer_kernel<true, true><<<grid, 256, 0, stream>>>(hA, off, rows_sorted, dis, hB, out, alpha);
    layer_kernel<false, true><<<grid, 256, 0, stream>>>(hB, off, rows_sorted, dis, nullptr, out, alpha);
}